// Round 1
// baseline (140.590 us; speedup 1.0000x reference)
//
#include <hip/hip_runtime.h>

#define BB 512
#define SS 4096
#define CC 8
#define NPOS (BB * SS)

#define PEN_BLOCKS 128   // 4 waves/block * 128 = 512 rows
#define CE_BLOCKS 1024
#define THREADS 256

// ws layout: [0] float ce_sum, [1] int nz_count, [2] int pen_sum
__global__ void init_ws_kernel(int* ws) {
    if (threadIdx.x < 4) ws[threadIdx.x] = 0;
}

__global__ __launch_bounds__(THREADS) void fused_loss_kernel(
    const float* __restrict__ logits, const int* __restrict__ targets,
    const int* __restrict__ structs, const float* __restrict__ cw,
    float* __restrict__ ce_sum, int* __restrict__ nz_sum, int* __restrict__ pen_sum)
{
    const int bid = blockIdx.x;
    const int wave = threadIdx.x >> 6;
    const int lane = threadIdx.x & 63;

    if (bid < PEN_BLOCKS) {
        // ---- structural penalty: one wave per row, 64 contiguous elems per lane ----
        const int row = bid * 4 + wave;
        const int* s = structs + row * SS;
        const int base = lane * 64;
        int run = 0, minp = 0, pat = 0;
        #pragma unroll 4
        for (int k = 0; k < 64; k++) {
            const int i = base + k;
            const int v0 = s[i];
            const int lp = (v0 == 1);
            const int rp = (v0 == 2);
            if (lp) {
                // exact stale-reuse clamps from the reference
                const int a  = (s[min(i + 1, SS - 1)] == 2);
                const int d1 = (s[min(i + 1, SS - 2)] == 3);
                const int r2 = (s[min(i + 2, SS - 1)] == 2);
                const int d2 = (s[min(i + 2, SS - 2)] == 3);
                const int r3 = (s[min(i + 3, SS - 1)] == 2);
                pat += 2 * a + 3 * (d1 & r2) + 4 * (d1 & d2 & r3);
            }
            run += lp - rp;
            minp = min(minp, run);
        }
        // cross-lane combine (in lane order): inclusive prefix sum of run
        int incl = run;
        #pragma unroll
        for (int sh = 1; sh < 64; sh <<= 1) {
            int n = __shfl_up(incl, sh, 64);
            if (lane >= sh) incl += n;
        }
        const int excl = incl - run;
        int cand = excl + minp;           // global min-prefix candidate from this lane
        int patAll = pat;
        #pragma unroll
        for (int sh = 32; sh; sh >>= 1) {
            cand = min(cand, __shfl_xor(cand, sh, 64));
            patAll += __shfl_xor(patAll, sh, 64);
        }
        const int Ptot = __shfl(incl, 63, 64);
        if (lane == 0) {
            // cand <= 0 always (lane0 empty prefix = 0); unmatched = -cand
            const int pen = patAll + Ptot - 2 * cand;
            atomicAdd(pen_sum, pen);
        }
    } else {
        // ---- weighted CE over positions ----
        const int tid = (bid - PEN_BLOCKS) * THREADS + threadIdx.x;
        const int nthreads = CE_BLOCKS * THREADS;
        const float4 wlo = ((const float4*)cw)[0];
        const float4 whi = ((const float4*)cw)[1];
        const float4* lg4 = (const float4*)logits;
        float ce = 0.f;
        int nz = 0;
        for (int i = tid; i < NPOS; i += nthreads) {
            const float4 lo = lg4[2 * i];
            const float4 hi = lg4[2 * i + 1];
            const int t = targets[i];
            float m = fmaxf(fmaxf(fmaxf(lo.x, lo.y), fmaxf(lo.z, lo.w)),
                            fmaxf(fmaxf(hi.x, hi.y), fmaxf(hi.z, hi.w)));
            float se = __expf(lo.x - m) + __expf(lo.y - m) + __expf(lo.z - m) + __expf(lo.w - m)
                     + __expf(hi.x - m) + __expf(hi.y - m) + __expf(hi.z - m) + __expf(hi.w - m);
            const float lse = m + __logf(se);
            const float4 h  = (t & 4) ? hi : lo;
            const float vx  = (t & 2) ? ((t & 1) ? h.w : h.z) : ((t & 1) ? h.y : h.x);
            const float4 wh = (t & 4) ? whi : wlo;
            const float wv  = (t & 2) ? ((t & 1) ? wh.w : wh.z) : ((t & 1) ? wh.y : wh.x);
            ce += (vx - lse) * wv;
            nz += (t != 0);
        }
        #pragma unroll
        for (int sh = 32; sh; sh >>= 1) {
            ce += __shfl_xor(ce, sh, 64);
            nz += __shfl_xor(nz, sh, 64);
        }
        __shared__ float s_ce[4];
        __shared__ int s_nz[4];
        if (lane == 0) { s_ce[wave] = ce; s_nz[wave] = nz; }
        __syncthreads();
        if (threadIdx.x == 0) {
            atomicAdd(ce_sum, s_ce[0] + s_ce[1] + s_ce[2] + s_ce[3]);
            atomicAdd(nz_sum, s_nz[0] + s_nz[1] + s_nz[2] + s_nz[3]);
        }
    }
}

__global__ void finalize_kernel(const float* ce_sum, const int* nz_sum,
                                const int* pen_sum, float* out)
{
    const float ce_loss = -(*ce_sum) / (float)NPOS;
    // penalty = mean_b(pen) / (nz / B) = pen_sum / nz
    const float penalty = (float)(*pen_sum) / (float)(*nz_sum);
    out[0] = ce_loss + 0.1f * penalty;
}

extern "C" void kernel_launch(void* const* d_in, const int* in_sizes, int n_in,
                              void* d_out, int out_size, void* d_ws, size_t ws_size,
                              hipStream_t stream) {
    const float* logits  = (const float*)d_in[0];
    const int*   targets = (const int*)d_in[1];
    const int*   structs = (const int*)d_in[2];
    const float* cw      = (const float*)d_in[3];
    float* out = (float*)d_out;

    float* ce_sum = (float*)d_ws;
    int*   nz_sum = (int*)d_ws + 1;
    int*   pen_sum = (int*)d_ws + 2;

    init_ws_kernel<<<1, 64, 0, stream>>>((int*)d_ws);
    fused_loss_kernel<<<PEN_BLOCKS + CE_BLOCKS, THREADS, 0, stream>>>(
        logits, targets, structs, cw, ce_sum, nz_sum, pen_sum);
    finalize_kernel<<<1, 1, 0, stream>>>(ce_sum, nz_sum, pen_sum, out);
}